// Round 8
// baseline (309.576 us; speedup 1.0000x reference)
//
#include <hip/hip_runtime.h>
#include <hip/hip_fp16.h>
#include <hip/hip_bf16.h>

// Problem constants (fixed by the reference)
#define NN 32768      // nodes
#define GG 64         // graphs
#define NPG 512       // nodes per graph
#define HD 128        // feature/hidden width
#define MAXD 64       // ELL pad (mean degree 16, P(>64) ~ 1e-26)
#define RSQRT_H 0.08838834764831845f  // 1/sqrt(128)

typedef _Float16 f16;
typedef __attribute__((ext_vector_type(4))) _Float16 f16x4;
typedef __attribute__((ext_vector_type(8))) _Float16 f16x8;
typedef __attribute__((ext_vector_type(4))) float f32x4;

// ---------------------------------------------------------------- ELL build
__global__ void k_fill(const int* __restrict__ src, const int* __restrict__ dst,
                       int* __restrict__ cursor, int* __restrict__ ell, int E) {
    int e = blockIdx.x * 256 + threadIdx.x;
    if (e < E) {
        int d = dst[e];
        int slot = atomicAdd(&cursor[d], 1);
        if (slot < MAXD) ell[d * MAXD + slot] = src[e];
    }
}

// ---------------------------------------------------------------- weight prep
// WT[n][k] = (f16)W[k][n] for the 4 projection weights (MFMA B-operand needs
// k contiguous at fixed n). Tiny: 4 x 128 x 128.
__global__ void k_wprep(const float* __restrict__ W1, const float* __restrict__ W2,
                        const float* __restrict__ Wq, const float* __restrict__ Wk,
                        f16* __restrict__ wt) {
    const float* Ws[4] = {W1, W2, Wq, Wk};
    int k = blockIdx.x, wsel = blockIdx.y, n = threadIdx.x;
    float v = Ws[wsel][k * HD + n];              // coalesced read along n
    wt[(size_t)wsel * HD * HD + n * HD + k] = (f16)v;
}

// ---------------------------------------------------------------- MFMA GEMM (x @ W1)
// [M,128]@[128,128], A fp32 cast in staging, out fp16. 64-row blocks, 4 waves.
// Fragment math (HW-verified r6/r7): A/B lane l -> row/col l&15, k=(l>>4)*8+j;
// C/D col = l&15, row = (l>>4)*4 + reg.
__global__ __launch_bounds__(256) void k_mgemm1(
    const float* __restrict__ Ain, const f16* __restrict__ WT,
    f16* __restrict__ out)
{
    __shared__ f16 Al[64][136];
    __shared__ f16 Wl[128][136];
    int t = threadIdx.x;
    int row0 = blockIdx.x * 64;
    int w = t >> 6, lane = t & 63, lr = lane & 15, lu = lane >> 4;

    const float4* W4 = (const float4*)WT;
#pragma unroll
    for (int i = 0; i < 8; ++i) {
        int idx = t + 256 * i;            // 2048 = 128 n-rows x 16 chunks
        *(float4*)&Wl[idx >> 4][(idx & 15) * 8] = W4[idx];
    }
    const float4* A32 = (const float4*)(Ain + (size_t)row0 * HD);
#pragma unroll
    for (int i = 0; i < 8; ++i) {
        int idx = t + 256 * i;            // 2048 = 64 rows x 32 chunks of 4 floats
        int r = idx >> 5, c4 = idx & 31;
        float4 v = A32[idx];
        f16x4 h = {(f16)v.x, (f16)v.y, (f16)v.z, (f16)v.w};
        *(f16x4*)&Al[r][c4 * 4] = h;
    }
    __syncthreads();

    f16x8 aq[4];
#pragma unroll
    for (int ks = 0; ks < 4; ++ks)
        aq[ks] = *(const f16x8*)&Al[w * 16 + lr][ks * 32 + lu * 8];
    f32x4 acc[8];
#pragma unroll
    for (int ni = 0; ni < 8; ++ni) {
        f32x4 c = {0.f, 0.f, 0.f, 0.f};
#pragma unroll
        for (int ks = 0; ks < 4; ++ks) {
            f16x8 b = *(const f16x8*)&Wl[ni * 16 + lr][ks * 32 + lu * 8];
            c = __builtin_amdgcn_mfma_f32_16x16x32_f16(aq[ks], b, c, 0, 0, 0);
        }
        acc[ni] = c;
    }
    __syncthreads();
#pragma unroll
    for (int ni = 0; ni < 8; ++ni)
#pragma unroll
        for (int j = 0; j < 4; ++j)
            Al[w * 16 + lu * 4 + j][ni * 16 + lr] = (f16)acc[ni][j];
    __syncthreads();
    float4* O4 = (float4*)(out + (size_t)row0 * HD);
#pragma unroll
    for (int i = 0; i < 4; ++i) {
        int idx = t + 256 * i;
        O4[idx] = *(float4*)&Al[idx >> 4][(idx & 15) * 8];
    }
}

// ---------------------------------------------------------------- fused agg + GEMM
// Agg phase: wave w aggregates nodes row0+16w..+15 (h = relu(A_hat t + b)),
// result straight into LDS as the MFMA A-tile (fp16). 4-edge unrolled gather.
__device__ __forceinline__ void agg_rows(
    const __half* __restrict__ tmat, const int* __restrict__ cursor,
    const int* __restrict__ ell, const float* __restrict__ bias,
    int row0, int w, int lane, f16 (*Al)[136], __half* __restrict__ hout)
{
    int lane2 = lane * 2;
    float b0 = bias[lane2], b1 = bias[lane2 + 1];
    for (int n = 0; n < 16; ++n) {
        int i = row0 + w * 16 + n;
        int cnt = min(cursor[i], MAXD);
        float di = rsqrtf((float)(cnt + 1));
        float2 sv = __half22float2(((const __half2*)(tmat + (size_t)i * HD))[lane]);
        float a0 = sv.x * (di * di), a1 = sv.y * (di * di);
        const int* row = ell + (size_t)i * MAXD;
        int e = 0;
        for (; e + 4 <= cnt; e += 4) {
            int s0 = row[e], s1 = row[e + 1], s2 = row[e + 2], s3 = row[e + 3];
            float q0 = rsqrtf((float)(min(cursor[s0], MAXD) + 1)) * di;
            float q1 = rsqrtf((float)(min(cursor[s1], MAXD) + 1)) * di;
            float q2 = rsqrtf((float)(min(cursor[s2], MAXD) + 1)) * di;
            float q3 = rsqrtf((float)(min(cursor[s3], MAXD) + 1)) * di;
            float2 v0 = __half22float2(((const __half2*)(tmat + (size_t)s0 * HD))[lane]);
            float2 v1 = __half22float2(((const __half2*)(tmat + (size_t)s1 * HD))[lane]);
            float2 v2 = __half22float2(((const __half2*)(tmat + (size_t)s2 * HD))[lane]);
            float2 v3 = __half22float2(((const __half2*)(tmat + (size_t)s3 * HD))[lane]);
            a0 += v0.x * q0 + v1.x * q1 + v2.x * q2 + v3.x * q3;
            a1 += v0.y * q0 + v1.y * q1 + v2.y * q2 + v3.y * q3;
        }
        for (; e < cnt; ++e) {
            int s0 = row[e];
            float q0 = rsqrtf((float)(min(cursor[s0], MAXD) + 1)) * di;
            float2 v0 = __half22float2(((const __half2*)(tmat + (size_t)s0 * HD))[lane]);
            a0 += v0.x * q0;
            a1 += v0.y * q0;
        }
        a0 = fmaxf(a0 + b0, 0.f);
        a1 = fmaxf(a1 + b1, 0.f);
        __half2 o;
        o.x = __float2half(a0); o.y = __float2half(a1);
        *(__half2*)&Al[w * 16 + n][lane2] = *(__half2*)&o;
        if (hout) ((__half2*)(hout + (size_t)i * HD))[lane] = o;
    }
}

// convA: h1 = relu(A_hat t1 + b1); t2 = h1 @ W2  (h1 not materialized)
__global__ __launch_bounds__(256) void k_convA(
    const __half* __restrict__ t1, const int* __restrict__ cursor,
    const int* __restrict__ ell, const float* __restrict__ b1,
    const f16* __restrict__ W2T, f16* __restrict__ t2)
{
    __shared__ f16 Al[64][136];
    __shared__ f16 Wl[128][136];
    int t = threadIdx.x;
    int row0 = blockIdx.x * 64;
    int w = t >> 6, lane = t & 63, lr = lane & 15, lu = lane >> 4;

    const float4* W4 = (const float4*)W2T;
#pragma unroll
    for (int i = 0; i < 8; ++i) {
        int idx = t + 256 * i;
        *(float4*)&Wl[idx >> 4][(idx & 15) * 8] = W4[idx];
    }
    agg_rows(t1, cursor, ell, b1, row0, w, lane, Al, nullptr);
    __syncthreads();

    f16x8 aq[4];
#pragma unroll
    for (int ks = 0; ks < 4; ++ks)
        aq[ks] = *(const f16x8*)&Al[w * 16 + lr][ks * 32 + lu * 8];
    f32x4 acc[8];
#pragma unroll
    for (int ni = 0; ni < 8; ++ni) {
        f32x4 c = {0.f, 0.f, 0.f, 0.f};
#pragma unroll
        for (int ks = 0; ks < 4; ++ks) {
            f16x8 b = *(const f16x8*)&Wl[ni * 16 + lr][ks * 32 + lu * 8];
            c = __builtin_amdgcn_mfma_f32_16x16x32_f16(aq[ks], b, c, 0, 0, 0);
        }
        acc[ni] = c;
    }
    __syncthreads();
#pragma unroll
    for (int ni = 0; ni < 8; ++ni)
#pragma unroll
        for (int j = 0; j < 4; ++j)
            Al[w * 16 + lu * 4 + j][ni * 16 + lr] = (f16)acc[ni][j];
    __syncthreads();
    float4* O4 = (float4*)(t2 + (size_t)row0 * HD);
#pragma unroll
    for (int i = 0; i < 4; ++i) {
        int idx = t + 256 * i;
        O4[idx] = *(float4*)&Al[idx >> 4][(idx & 15) * 8];
    }
}

// convB: h2 = relu(A_hat t2 + b2) -> written out; q = h2@Wq+bq; k = h2@Wk+bk.
// Wk reloaded into the same Wl buffer (keeps LDS at 52KB -> 3 blocks/CU).
__global__ __launch_bounds__(256) void k_convB(
    const __half* __restrict__ t2, const int* __restrict__ cursor,
    const int* __restrict__ ell, const float* __restrict__ b2,
    const f16* __restrict__ WqT, const float* __restrict__ bq,
    const f16* __restrict__ WkT, const float* __restrict__ bk,
    __half* __restrict__ hout, f16* __restrict__ qout, f16* __restrict__ kout)
{
    __shared__ f16 Al[64][136];
    __shared__ f16 Wl[128][136];
    int t = threadIdx.x;
    int row0 = blockIdx.x * 64;
    int w = t >> 6, lane = t & 63, lr = lane & 15, lu = lane >> 4;

    const float4* Wq4 = (const float4*)WqT;
#pragma unroll
    for (int i = 0; i < 8; ++i) {
        int idx = t + 256 * i;
        *(float4*)&Wl[idx >> 4][(idx & 15) * 8] = Wq4[idx];
    }
    agg_rows(t2, cursor, ell, b2, row0, w, lane, Al, hout);
    __syncthreads();                      // Al + Wl(q) ready

    f16x8 aq[4];
#pragma unroll
    for (int ks = 0; ks < 4; ++ks)
        aq[ks] = *(const f16x8*)&Al[w * 16 + lr][ks * 32 + lu * 8];
    f32x4 acc[8];
#pragma unroll
    for (int ni = 0; ni < 8; ++ni) {
        f32x4 c = {0.f, 0.f, 0.f, 0.f};
#pragma unroll
        for (int ks = 0; ks < 4; ++ks) {
            f16x8 b = *(const f16x8*)&Wl[ni * 16 + lr][ks * 32 + lu * 8];
            c = __builtin_amdgcn_mfma_f32_16x16x32_f16(aq[ks], b, c, 0, 0, 0);
        }
        acc[ni] = c;
    }
    __syncthreads();                      // everyone done with Al(aq) + Wl(q)
    const float4* Wk4 = (const float4*)WkT;
#pragma unroll
    for (int i = 0; i < 8; ++i) {         // reload Wl with Wk
        int idx = t + 256 * i;
        *(float4*)&Wl[idx >> 4][(idx & 15) * 8] = Wk4[idx];
    }
#pragma unroll
    for (int ni = 0; ni < 8; ++ni)        // restage q result (+bias) into Al
#pragma unroll
        for (int j = 0; j < 4; ++j)
            Al[w * 16 + lu * 4 + j][ni * 16 + lr] =
                (f16)(acc[ni][j] + bq[ni * 16 + lr]);
    __syncthreads();                      // Al(q-result) + Wl(k) visible
    {
        float4* O4 = (float4*)(qout + (size_t)row0 * HD);
#pragma unroll
        for (int i = 0; i < 4; ++i) {
            int idx = t + 256 * i;
            O4[idx] = *(float4*)&Al[idx >> 4][(idx & 15) * 8];
        }
    }
#pragma unroll
    for (int ni = 0; ni < 8; ++ni) {
        f32x4 c = {0.f, 0.f, 0.f, 0.f};
#pragma unroll
        for (int ks = 0; ks < 4; ++ks) {
            f16x8 b = *(const f16x8*)&Wl[ni * 16 + lr][ks * 32 + lu * 8];
            c = __builtin_amdgcn_mfma_f32_16x16x32_f16(aq[ks], b, c, 0, 0, 0);
        }
        acc[ni] = c;
    }
    __syncthreads();                      // q-stores done reading Al
#pragma unroll
    for (int ni = 0; ni < 8; ++ni)
#pragma unroll
        for (int j = 0; j < 4; ++j)
            Al[w * 16 + lu * 4 + j][ni * 16 + lr] =
                (f16)(acc[ni][j] + bk[ni * 16 + lr]);
    __syncthreads();
    {
        float4* O4 = (float4*)(kout + (size_t)row0 * HD);
#pragma unroll
        for (int i = 0; i < 4; ++i) {
            int idx = t + 256 * i;
            O4[idx] = *(float4*)&Al[idx >> 4][(idx & 15) * 8];
        }
    }
}

// ---------------------------------------------------------------- attention
// MFMA QK^T, double-buffered K staging (one barrier/tile; loads of tile mt+1
// overlap MFMAs of tile mt). S strip in regs; column sums -> wpart slices.
__global__ __launch_bounds__(256, 2) void k_attn(
    const __half* __restrict__ qh,  // [N][128] fp16
    const __half* __restrict__ kh,  // [N][128] fp16
    float* __restrict__ wpart)      // [64*8][512]
{
    __shared__ f16 Kl[2][64][136];
    __shared__ float wlp[4][512];
    int t = threadIdx.x;
    int g = blockIdx.x >> 3;
    int qt = blockIdx.x & 7;
    int w = t >> 6, lane = t & 63;
    int lr = lane & 15, lu = lane >> 4;
    int qrow0 = g * NPG + qt * 64;

    f16x8 aq[4];
    {
        const f16* qp = (const f16*)qh + (size_t)(qrow0 + w * 16 + lr) * HD + lu * 8;
#pragma unroll
        for (int ks = 0; ks < 4; ++ks)
            aq[ks] = *(const f16x8*)(qp + ks * 32);
    }
    // stage tile 0 into buffer 0
    {
        const float4* ks4 = (const float4*)(kh + (size_t)(g * NPG) * HD);
#pragma unroll
        for (int i = 0; i < 4; ++i) {
            int idx = t + 256 * i;
            *(float4*)&Kl[0][idx >> 4][(idx & 15) * 8] = ks4[idx];
        }
    }

    f32x4 p[8][4];       // [mt][ni], statically indexed
#pragma unroll
    for (int mt = 0; mt < 8; ++mt) {
        __syncthreads();                 // buf[mt&1] ready; prev compute done
        if (mt < 7) {
            const float4* ks4 = (const float4*)(kh + (size_t)(g * NPG + (mt + 1) * 64) * HD);
#pragma unroll
            for (int i = 0; i < 4; ++i) {
                int idx = t + 256 * i;
                *(float4*)&Kl[(mt + 1) & 1][idx >> 4][(idx & 15) * 8] = ks4[idx];
            }
        }
#pragma unroll
        for (int ni = 0; ni < 4; ++ni) {
            f32x4 acc = {0.f, 0.f, 0.f, 0.f};
#pragma unroll
            for (int ks = 0; ks < 4; ++ks) {
                f16x8 b = *(const f16x8*)&Kl[mt & 1][ni * 16 + lr][ks * 32 + lu * 8];
                acc = __builtin_amdgcn_mfma_f32_16x16x32_f16(aq[ks], b, acc, 0, 0, 0);
            }
            p[mt][ni] = acc;
        }
    }

    // row max per reg j (row = 16w + 4*lu + j)
    float mrow[4], linv[4];
#pragma unroll
    for (int j = 0; j < 4; ++j) {
        float m = p[0][0][j];
#pragma unroll
        for (int mt = 0; mt < 8; ++mt)
#pragma unroll
            for (int ni = 0; ni < 4; ++ni) m = fmaxf(m, p[mt][ni][j]);
        m = fmaxf(m, __shfl_xor(m, 1));
        m = fmaxf(m, __shfl_xor(m, 2));
        m = fmaxf(m, __shfl_xor(m, 4));
        m = fmaxf(m, __shfl_xor(m, 8));
        mrow[j] = m;
    }
#pragma unroll
    for (int mt = 0; mt < 8; ++mt)
#pragma unroll
        for (int ni = 0; ni < 4; ++ni)
#pragma unroll
            for (int j = 0; j < 4; ++j)
                p[mt][ni][j] = __expf((p[mt][ni][j] - mrow[j]) * RSQRT_H);
#pragma unroll
    for (int j = 0; j < 4; ++j) {
        float l = 0.f;
#pragma unroll
        for (int mt = 0; mt < 8; ++mt)
#pragma unroll
            for (int ni = 0; ni < 4; ++ni) l += p[mt][ni][j];
        l += __shfl_xor(l, 1);
        l += __shfl_xor(l, 2);
        l += __shfl_xor(l, 4);
        l += __shfl_xor(l, 8);
        linv[j] = 1.f / l;
    }
    // column sums of normalized attention -> per-wave slice (no atomics)
#pragma unroll
    for (int mt = 0; mt < 8; ++mt)
#pragma unroll
        for (int ni = 0; ni < 4; ++ni) {
            float pc = p[mt][ni][0] * linv[0] + p[mt][ni][1] * linv[1]
                     + p[mt][ni][2] * linv[2] + p[mt][ni][3] * linv[3];
            pc += __shfl_xor(pc, 16);
            pc += __shfl_xor(pc, 32);
            if (lu == 0) wlp[w][mt * 64 + ni * 16 + lr] = pc;
        }
    __syncthreads();
    float* wp = wpart + ((size_t)(g * 8 + qt)) * NPG;
    wp[t] = (wlp[0][t] + wlp[1][t] + wlp[2][t] + wlp[3][t]) * (1.f / NPG);
    wp[t + 256] = (wlp[0][t + 256] + wlp[1][t + 256] + wlp[2][t + 256]
                 + wlp[3][t + 256]) * (1.f / NPG);
}

// ---------------------------------------------------------------- pool + head
// One block per graph: w = sum of qt slices; u = sum_m w[m] h[m]; then MLP.
__global__ __launch_bounds__(256) void k_poolhead(
    const float* __restrict__ wpart, const __half* __restrict__ h,
    const float* __restrict__ Wv, const float* __restrict__ bv,
    const float* __restrict__ Wh1, const float* __restrict__ bh1,
    const float* __restrict__ Wh2, const float* __restrict__ bh2,
    float* __restrict__ out)
{
    __shared__ float wloc[512];
    __shared__ float upar[2][128];
    __shared__ float ul[128];
    __shared__ float pl[128];
    __shared__ float r1l[64];
    int g = blockIdx.x, t = threadIdx.x;
    {
        float w0 = 0.f, w1 = 0.f;
#pragma unroll
        for (int qt = 0; qt < 8; ++qt) {
            const float* wp = wpart + ((size_t)(g * 8 + qt)) * NPG;
            w0 += wp[t]; w1 += wp[t + 256];
        }
        wloc[t] = w0; wloc[t + 256] = w1;
    }
    __syncthreads();
    int col = t & 127, half = t >> 7;
    const __half* hg = h + ((size_t)g * NPG + half * 256) * HD;
    float u = 0.f;
#pragma unroll 4
    for (int m = 0; m < 256; ++m)
        u += wloc[half * 256 + m] * __half2float(hg[(size_t)m * HD + col]);
    upar[half][col] = u;
    __syncthreads();
    if (t < 128) ul[t] = upar[0][t] + upar[1][t];
    __syncthreads();
    if (t < 128) {
        float pv = bv[t];
        for (int d = 0; d < HD; ++d) pv += ul[d] * Wv[d * HD + t];
        pl[t] = pv;
    }
    __syncthreads();
    if (t < 64) {
        float r1 = bh1[t];
        for (int d = 0; d < HD; ++d) r1 += pl[d] * Wh1[d * 64 + t];
        r1l[t] = fmaxf(r1, 0.f);
    }
    __syncthreads();
    if (t == 0) {
        float o = bh2[0];
        for (int j = 0; j < 64; ++j) o += r1l[j] * Wh2[j];
        out[g] = o;
    }
}

// ---------------------------------------------------------------- launch
extern "C" void kernel_launch(void* const* d_in, const int* in_sizes, int n_in,
                              void* d_out, int out_size, void* d_ws, size_t ws_size,
                              hipStream_t stream) {
    const float* x   = (const float*)d_in[0];
    const int* edge  = (const int*)d_in[1];
    // d_in[2] = batch (unused: batch = arange // 512 exactly)
    const float* W1  = (const float*)d_in[3];
    const float* b1  = (const float*)d_in[4];
    const float* W2  = (const float*)d_in[5];
    const float* b2  = (const float*)d_in[6];
    const float* Wq  = (const float*)d_in[7];
    const float* bq  = (const float*)d_in[8];
    const float* Wk  = (const float*)d_in[9];
    const float* bk  = (const float*)d_in[10];
    const float* Wv  = (const float*)d_in[11];
    const float* bv  = (const float*)d_in[12];
    const float* Wh1 = (const float*)d_in[13];
    const float* bh1 = (const float*)d_in[14];
    const float* Wh2 = (const float*)d_in[15];
    const float* bh2 = (const float*)d_in[16];
    float* out = (float*)d_out;

    int E = in_sizes[1] / 2;
    const int* src = edge;
    const int* dst = edge + E;

    // workspace layout (~51 MB):
    //  region1 [16MB]: t1 fp16 | t2 fp16
    //  region2 [16MB]: h2 fp16 | q fp16
    //  region3 [16MB]: ell int[N][64] (8MB, lives through convB) | k fp16 (8MB)
    //  wpart | cursor | wtb
    f16* t1 = (f16*)d_ws;                            // [N][128] fp16
    f16* t2 = t1 + (size_t)NN * HD;                  // [N][128] fp16
    __half* h2 = (__half*)(t2 + (size_t)NN * HD);    // [N][128] fp16
    f16* qh = (f16*)(h2 + (size_t)NN * HD);          // [N][128] fp16
    int* ell = (int*)(qh + (size_t)NN * HD);         // [N][64]
    f16* kh = (f16*)(ell + (size_t)NN * MAXD);       // [N][128] fp16
    float* wpart = (float*)(kh + (size_t)NN * HD);   // [64*8][512]
    int* cursor = (int*)(wpart + GG * 8 * NPG);      // [N]
    f16* wtb    = (f16*)(cursor + NN);               // [4][128][128] fp16
    f16* W1T = wtb, *W2T = wtb + HD * HD, *WqT = wtb + 2 * HD * HD,
       * WkT = wtb + 3 * HD * HD;

    int eb = (E + 255) / 256;

    // graph structure + weight prep
    hipMemsetAsync(cursor, 0, NN * sizeof(int), stream);
    k_fill<<<eb, 256, 0, stream>>>(src, dst, cursor, ell, E);
    k_wprep<<<dim3(HD, 4), HD, 0, stream>>>(W1, W2, Wq, Wk, wtb);

    // t1 = x @ W1 (fp32 A cast in staging)
    k_mgemm1<<<NN / 64, 256, 0, stream>>>(x, W1T, t1);
    // conv1-agg fused into conv2 GEMM: t2 = relu(A_hat t1 + b1) @ W2
    k_convA<<<NN / 64, 256, 0, stream>>>((const __half*)t1, cursor, ell, b1, W2T, t2);
    // conv2-agg fused into q/k projections; h2 materialized for pooling
    k_convB<<<NN / 64, 256, 0, stream>>>((const __half*)t2, cursor, ell, b2,
                                         WqT, bq, WkT, bk, h2, qh, kh);
    // attention column weights via MFMA (double-buffered K)
    k_attn<<<GG * 8, 256, 0, stream>>>((const __half*)qh, (const __half*)kh, wpart);
    // pool + MLP head, one block per graph
    k_poolhead<<<GG, 256, 0, stream>>>(wpart, h2, Wv, bv, Wh1, bh1, Wh2, bh2, out);
}

// Round 9
// 251.378 us; speedup vs baseline: 1.2315x; 1.2315x over previous
//
#include <hip/hip_runtime.h>
#include <hip/hip_fp16.h>
#include <hip/hip_bf16.h>

// Problem constants (fixed by the reference)
#define NN 32768      // nodes
#define GG 64         // graphs
#define NPG 512       // nodes per graph
#define HD 128        // feature/hidden width
#define MAXD 64       // ELL pad (mean degree 16, P(>64) ~ 1e-26)
#define RSQRT_H 0.08838834764831845f  // 1/sqrt(128)

typedef _Float16 f16;
typedef __attribute__((ext_vector_type(4))) _Float16 f16x4;
typedef __attribute__((ext_vector_type(8))) _Float16 f16x8;
typedef __attribute__((ext_vector_type(4))) float f32x4;

// ---------------------------------------------------------------- ELL build
__global__ void k_fill(const int* __restrict__ src, const int* __restrict__ dst,
                       int* __restrict__ cursor, int* __restrict__ ell, int E) {
    int e = blockIdx.x * 256 + threadIdx.x;
    if (e < E) {
        int d = dst[e];
        int slot = atomicAdd(&cursor[d], 1);
        if (slot < MAXD) ell[d * MAXD + slot] = src[e];
    }
}

// ---------------------------------------------------------------- weight prep
// WT[n][k] = (f16)W[k][n] (MFMA B-operand needs k contiguous at fixed n).
__global__ void k_wprep(const float* __restrict__ W1, const float* __restrict__ W2,
                        const float* __restrict__ Wq, const float* __restrict__ Wk,
                        f16* __restrict__ wt) {
    const float* Ws[4] = {W1, W2, Wq, Wk};
    int k = blockIdx.x, wsel = blockIdx.y, n = threadIdx.x;
    float v = Ws[wsel][k * HD + n];              // coalesced read along n
    wt[(size_t)wsel * HD * HD + n * HD + k] = (f16)v;
}

// ---------------------------------------------------------------- MFMA GEMM
// [M,128]@[128,128] fp16 out. 64-row blocks, 4 waves, wave = 16 rows x 128
// cols = 32 mfma_f32_16x16x32_f16. Fragment math HW-verified (r6/r7):
// A/B lane l -> row/col l&15, k=(l>>4)*8+j; C/D col=l&15, row=(l>>4)*4+reg.
// DO NOT fuse the edge-gather into this kernel: r8 showed the gather is
// latency-bound and needs one-wave-per-node TLP (77us fused vs ~25us split).
template<int AF32, int BIAS>
__global__ __launch_bounds__(256) void k_mgemm(
    const void* __restrict__ Ain, const f16* __restrict__ WT,
    const float* __restrict__ bias, f16* __restrict__ out)
{
    __shared__ f16 Al[64][136];
    __shared__ f16 Wl[128][136];
    int t = threadIdx.x;
    int row0 = blockIdx.x * 64;
    int w = t >> 6, lane = t & 63, lr = lane & 15, lu = lane >> 4;

    if (AF32) {   // stage + cast fp32 A
        const float4* A32 = (const float4*)((const float*)Ain + (size_t)row0 * HD);
#pragma unroll
        for (int i = 0; i < 8; ++i) {
            int idx = t + 256 * i;        // 2048 = 64 rows x 32 chunks of 4 floats
            int r = idx >> 5, c4 = idx & 31;
            float4 v = A32[idx];
            f16x4 h = {(f16)v.x, (f16)v.y, (f16)v.z, (f16)v.w};
            *(f16x4*)&Al[r][c4 * 4] = h;
        }
    } else {      // stage fp16 A
        const float4* A16 = (const float4*)((const f16*)Ain + (size_t)row0 * HD);
#pragma unroll
        for (int i = 0; i < 4; ++i) {
            int idx = t + 256 * i;        // 1024 = 64 rows x 16 chunks of 8 f16
            *(float4*)&Al[idx >> 4][(idx & 15) * 8] = A16[idx];
        }
    }
    const float4* W4 = (const float4*)WT;
#pragma unroll
    for (int i = 0; i < 8; ++i) {
        int idx = t + 256 * i;            // 2048 = 128 n-rows x 16 chunks
        *(float4*)&Wl[idx >> 4][(idx & 15) * 8] = W4[idx];
    }
    __syncthreads();

    f16x8 aq[4];
#pragma unroll
    for (int ks = 0; ks < 4; ++ks)
        aq[ks] = *(const f16x8*)&Al[w * 16 + lr][ks * 32 + lu * 8];

    f32x4 acc[8];
#pragma unroll
    for (int ni = 0; ni < 8; ++ni) {
        f32x4 c = {0.f, 0.f, 0.f, 0.f};
#pragma unroll
        for (int ks = 0; ks < 4; ++ks) {
            f16x8 b = *(const f16x8*)&Wl[ni * 16 + lr][ks * 32 + lu * 8];
            c = __builtin_amdgcn_mfma_f32_16x16x32_f16(aq[ks], b, c, 0, 0, 0);
        }
        acc[ni] = c;
    }

    // epilogue: restage fp16 result in Al (dead) for coalesced float4 stores
    __syncthreads();
#pragma unroll
    for (int ni = 0; ni < 8; ++ni)
#pragma unroll
        for (int j = 0; j < 4; ++j) {
            float v = acc[ni][j];
            if (BIAS) v += bias[ni * 16 + lr];
            Al[w * 16 + lu * 4 + j][ni * 16 + lr] = (f16)v;
        }
    __syncthreads();
    float4* O4 = (float4*)(out + (size_t)row0 * HD);
#pragma unroll
    for (int i = 0; i < 4; ++i) {
        int idx = t + 256 * i;
        O4[idx] = *(float4*)&Al[idx >> 4][(idx & 15) * 8];
    }
}

// ---------------------------------------------------------------- aggregation
// one 64-lane wave per node (4 nodes / 256-thread block); fp16 gather rows
// (256B coalesced per row), fp32 accumulate, fp16 out. 4-edge ILP unroll.
__global__ __launch_bounds__(256) void k_agg(
    const __half* __restrict__ tmat, const int* __restrict__ cursor,
    const int* __restrict__ ell, const float* __restrict__ bias,
    __half* __restrict__ hout)
{
    int t = threadIdx.x;
    int i = blockIdx.x * 4 + (t >> 6);   // node
    int lane = t & 63;                   // feature pair index
    int cnt = min(cursor[i], MAXD);
    float di = rsqrtf((float)(cnt + 1));
    float2 sv = __half22float2(((const __half2*)(tmat + (size_t)i * HD))[lane]);
    float acc0 = sv.x * (di * di);
    float acc1 = sv.y * (di * di);
    const int* row = ell + (size_t)i * MAXD;
    int e = 0;
    for (; e + 4 <= cnt; e += 4) {       // 4-edge ILP unroll
        int s0 = row[e], s1 = row[e + 1], s2 = row[e + 2], s3 = row[e + 3];
        float q0 = rsqrtf((float)(min(cursor[s0], MAXD) + 1)) * di;
        float q1 = rsqrtf((float)(min(cursor[s1], MAXD) + 1)) * di;
        float q2 = rsqrtf((float)(min(cursor[s2], MAXD) + 1)) * di;
        float q3 = rsqrtf((float)(min(cursor[s3], MAXD) + 1)) * di;
        float2 v0 = __half22float2(((const __half2*)(tmat + (size_t)s0 * HD))[lane]);
        float2 v1 = __half22float2(((const __half2*)(tmat + (size_t)s1 * HD))[lane]);
        float2 v2 = __half22float2(((const __half2*)(tmat + (size_t)s2 * HD))[lane]);
        float2 v3 = __half22float2(((const __half2*)(tmat + (size_t)s3 * HD))[lane]);
        acc0 += v0.x * q0 + v1.x * q1 + v2.x * q2 + v3.x * q3;
        acc1 += v0.y * q0 + v1.y * q1 + v2.y * q2 + v3.y * q3;
    }
    for (; e < cnt; ++e) {
        int s0 = row[e];
        float q0 = rsqrtf((float)(min(cursor[s0], MAXD) + 1)) * di;
        float2 v0 = __half22float2(((const __half2*)(tmat + (size_t)s0 * HD))[lane]);
        acc0 += v0.x * q0;
        acc1 += v0.y * q0;
    }
    __half2 o;
    o.x = __float2half(fmaxf(acc0 + bias[lane * 2], 0.f));
    o.y = __float2half(fmaxf(acc1 + bias[lane * 2 + 1], 0.f));
    ((__half2*)(hout + (size_t)i * HD))[lane] = o;
}

// ---------------------------------------------------------------- attention
// MFMA QK^T, double-buffered K staging (one barrier/tile; loads of tile mt+1
// overlap MFMAs of tile mt). S strip in regs; column sums -> wpart slices.
__global__ __launch_bounds__(256, 2) void k_attn(
    const __half* __restrict__ qh,  // [N][128] fp16
    const __half* __restrict__ kh,  // [N][128] fp16
    float* __restrict__ wpart)      // [64*8][512]
{
    __shared__ f16 Kl[2][64][136];
    __shared__ float wlp[4][512];
    int t = threadIdx.x;
    int g = blockIdx.x >> 3;
    int qt = blockIdx.x & 7;
    int w = t >> 6, lane = t & 63;
    int lr = lane & 15, lu = lane >> 4;
    int qrow0 = g * NPG + qt * 64;

    f16x8 aq[4];
    {
        const f16* qp = (const f16*)qh + (size_t)(qrow0 + w * 16 + lr) * HD + lu * 8;
#pragma unroll
        for (int ks = 0; ks < 4; ++ks)
            aq[ks] = *(const f16x8*)(qp + ks * 32);
    }
    // stage tile 0 into buffer 0
    {
        const float4* ks4 = (const float4*)(kh + (size_t)(g * NPG) * HD);
#pragma unroll
        for (int i = 0; i < 4; ++i) {
            int idx = t + 256 * i;
            *(float4*)&Kl[0][idx >> 4][(idx & 15) * 8] = ks4[idx];
        }
    }

    f32x4 p[8][4];       // [mt][ni], statically indexed
#pragma unroll
    for (int mt = 0; mt < 8; ++mt) {
        __syncthreads();                 // buf[mt&1] ready; prev compute done
        if (mt < 7) {
            const float4* ks4 = (const float4*)(kh + (size_t)(g * NPG + (mt + 1) * 64) * HD);
#pragma unroll
            for (int i = 0; i < 4; ++i) {
                int idx = t + 256 * i;
                *(float4*)&Kl[(mt + 1) & 1][idx >> 4][(idx & 15) * 8] = ks4[idx];
            }
        }
#pragma unroll
        for (int ni = 0; ni < 4; ++ni) {
            f32x4 acc = {0.f, 0.f, 0.f, 0.f};
#pragma unroll
            for (int ks = 0; ks < 4; ++ks) {
                f16x8 b = *(const f16x8*)&Kl[mt & 1][ni * 16 + lr][ks * 32 + lu * 8];
                acc = __builtin_amdgcn_mfma_f32_16x16x32_f16(aq[ks], b, acc, 0, 0, 0);
            }
            p[mt][ni] = acc;
        }
    }

    // row max per reg j (row = 16w + 4*lu + j)
    float mrow[4], linv[4];
#pragma unroll
    for (int j = 0; j < 4; ++j) {
        float m = p[0][0][j];
#pragma unroll
        for (int mt = 0; mt < 8; ++mt)
#pragma unroll
            for (int ni = 0; ni < 4; ++ni) m = fmaxf(m, p[mt][ni][j]);
        m = fmaxf(m, __shfl_xor(m, 1));
        m = fmaxf(m, __shfl_xor(m, 2));
        m = fmaxf(m, __shfl_xor(m, 4));
        m = fmaxf(m, __shfl_xor(m, 8));
        mrow[j] = m;
    }
#pragma unroll
    for (int mt = 0; mt < 8; ++mt)
#pragma unroll
        for (int ni = 0; ni < 4; ++ni)
#pragma unroll
            for (int j = 0; j < 4; ++j)
                p[mt][ni][j] = __expf((p[mt][ni][j] - mrow[j]) * RSQRT_H);
#pragma unroll
    for (int j = 0; j < 4; ++j) {
        float l = 0.f;
#pragma unroll
        for (int mt = 0; mt < 8; ++mt)
#pragma unroll
            for (int ni = 0; ni < 4; ++ni) l += p[mt][ni][j];
        l += __shfl_xor(l, 1);
        l += __shfl_xor(l, 2);
        l += __shfl_xor(l, 4);
        l += __shfl_xor(l, 8);
        linv[j] = 1.f / l;
    }
    // column sums of normalized attention -> per-wave slice (no atomics)
#pragma unroll
    for (int mt = 0; mt < 8; ++mt)
#pragma unroll
        for (int ni = 0; ni < 4; ++ni) {
            float pc = p[mt][ni][0] * linv[0] + p[mt][ni][1] * linv[1]
                     + p[mt][ni][2] * linv[2] + p[mt][ni][3] * linv[3];
            pc += __shfl_xor(pc, 16);
            pc += __shfl_xor(pc, 32);
            if (lu == 0) wlp[w][mt * 64 + ni * 16 + lr] = pc;
        }
    __syncthreads();
    float* wp = wpart + ((size_t)(g * 8 + qt)) * NPG;
    wp[t] = (wlp[0][t] + wlp[1][t] + wlp[2][t] + wlp[3][t]) * (1.f / NPG);
    wp[t + 256] = (wlp[0][t + 256] + wlp[1][t + 256] + wlp[2][t + 256]
                 + wlp[3][t + 256]) * (1.f / NPG);
}

// ---------------------------------------------------------------- pool + head
// One block per graph: w = sum of qt slices; u = sum_m w[m] h[m]; then MLP.
__global__ __launch_bounds__(256) void k_poolhead(
    const float* __restrict__ wpart, const __half* __restrict__ h,
    const float* __restrict__ Wv, const float* __restrict__ bv,
    const float* __restrict__ Wh1, const float* __restrict__ bh1,
    const float* __restrict__ Wh2, const float* __restrict__ bh2,
    float* __restrict__ out)
{
    __shared__ float wloc[512];
    __shared__ float upar[2][128];
    __shared__ float ul[128];
    __shared__ float pl[128];
    __shared__ float r1l[64];
    int g = blockIdx.x, t = threadIdx.x;
    {
        float w0 = 0.f, w1 = 0.f;
#pragma unroll
        for (int qt = 0; qt < 8; ++qt) {
            const float* wp = wpart + ((size_t)(g * 8 + qt)) * NPG;
            w0 += wp[t]; w1 += wp[t + 256];
        }
        wloc[t] = w0; wloc[t + 256] = w1;
    }
    __syncthreads();
    int col = t & 127, half = t >> 7;
    const __half* hg = h + ((size_t)g * NPG + half * 256) * HD;
    float u = 0.f;
#pragma unroll 4
    for (int m = 0; m < 256; ++m)
        u += wloc[half * 256 + m] * __half2float(hg[(size_t)m * HD + col]);
    upar[half][col] = u;
    __syncthreads();
    if (t < 128) ul[t] = upar[0][t] + upar[1][t];
    __syncthreads();
    if (t < 128) {
        float pv = bv[t];
        for (int d = 0; d < HD; ++d) pv += ul[d] * Wv[d * HD + t];
        pl[t] = pv;
    }
    __syncthreads();
    if (t < 64) {
        float r1 = bh1[t];
        for (int d = 0; d < HD; ++d) r1 += pl[d] * Wh1[d * 64 + t];
        r1l[t] = fmaxf(r1, 0.f);
    }
    __syncthreads();
    if (t == 0) {
        float o = bh2[0];
        for (int j = 0; j < 64; ++j) o += r1l[j] * Wh2[j];
        out[g] = o;
    }
}

// ---------------------------------------------------------------- launch
extern "C" void kernel_launch(void* const* d_in, const int* in_sizes, int n_in,
                              void* d_out, int out_size, void* d_ws, size_t ws_size,
                              hipStream_t stream) {
    const float* x   = (const float*)d_in[0];
    const int* edge  = (const int*)d_in[1];
    // d_in[2] = batch (unused: batch = arange // 512 exactly)
    const float* W1  = (const float*)d_in[3];
    const float* b1  = (const float*)d_in[4];
    const float* W2  = (const float*)d_in[5];
    const float* b2  = (const float*)d_in[6];
    const float* Wq  = (const float*)d_in[7];
    const float* bq  = (const float*)d_in[8];
    const float* Wk  = (const float*)d_in[9];
    const float* bk  = (const float*)d_in[10];
    const float* Wv  = (const float*)d_in[11];
    const float* bv  = (const float*)d_in[12];
    const float* Wh1 = (const float*)d_in[13];
    const float* bh1 = (const float*)d_in[14];
    const float* Wh2 = (const float*)d_in[15];
    const float* bh2 = (const float*)d_in[16];
    float* out = (float*)d_out;

    int E = in_sizes[1] / 2;
    const int* src = edge;
    const int* dst = edge + E;

    // workspace layout (~51 MB):
    //  region1 [16MB]: tmat fp16 (conv) -> qh fp16 | kh fp16
    //  region2 [16MB]: hbuf fp16 (first 8MB)
    //  region3 [16MB]: ell int[N][64] (8MB)
    //  wpart | cursor | wtb
    f16* tmat = (f16*)d_ws;                          // [N][128] fp16
    f16* qh   = tmat;                                // overlays tmat after aggs
    f16* kh   = qh + (size_t)NN * HD;                // second 8MB of region1
    __half* hbuf = (__half*)(kh + (size_t)NN * HD);  // region2 (8MB used)
    int* ell = (int*)((f16*)hbuf + 2 * (size_t)NN * HD);  // region3
    float* wpart = (float*)(ell + (size_t)NN * MAXD);     // [64*8][512]
    int* cursor = (int*)(wpart + GG * 8 * NPG);      // [N]
    f16* wtb    = (f16*)(cursor + NN);               // [4][128][128] fp16
    f16* W1T = wtb, *W2T = wtb + HD * HD, *WqT = wtb + 2 * HD * HD,
       * WkT = wtb + 3 * HD * HD;

    int eb = (E + 255) / 256;

    // graph structure + weight prep
    hipMemsetAsync(cursor, 0, NN * sizeof(int), stream);
    k_fill<<<eb, 256, 0, stream>>>(src, dst, cursor, ell, E);
    k_wprep<<<dim3(HD, 4), HD, 0, stream>>>(W1, W2, Wq, Wk, wtb);

    // conv1 (A = x fp32, cast in staging)
    k_mgemm<1, 0><<<NN / 64, 256, 0, stream>>>(x, W1T, nullptr, tmat);
    k_agg<<<NN / 4, 256, 0, stream>>>((const __half*)tmat, cursor, ell, b1, hbuf);
    // conv2
    k_mgemm<0, 0><<<NN / 64, 256, 0, stream>>>(hbuf, W2T, nullptr, tmat);
    k_agg<<<NN / 4, 256, 0, stream>>>((const __half*)tmat, cursor, ell, b2, hbuf);
    // q, k projections (qh overlays dead tmat)
    k_mgemm<0, 1><<<NN / 64, 256, 0, stream>>>(hbuf, WqT, bq, qh);
    k_mgemm<0, 1><<<NN / 64, 256, 0, stream>>>(hbuf, WkT, bk, kh);
    // attention column weights via MFMA (double-buffered K)
    k_attn<<<GG * 8, 256, 0, stream>>>((const __half*)qh, (const __half*)kh, wpart);
    // pool + MLP head, one block per graph
    k_poolhead<<<GG, 256, 0, stream>>>(wpart, hbuf, Wv, bv, Wh1, bh1, Wh2, bh2, out);
}

// Round 12
// 239.869 us; speedup vs baseline: 1.2906x; 1.0480x over previous
//
#include <hip/hip_runtime.h>
#include <hip/hip_fp16.h>
#include <hip/hip_bf16.h>

// Problem constants (fixed by the reference)
#define NN 32768      // nodes
#define GG 64         // graphs
#define NPG 512       // nodes per graph
#define HD 128        // feature/hidden width
#define MAXD 64       // ELL pad (mean degree 16, P(>64) ~ 1e-26)
#define RSQRT_H 0.08838834764831845f  // 1/sqrt(128)

typedef _Float16 f16;
typedef __attribute__((ext_vector_type(4))) _Float16 f16x4;
typedef __attribute__((ext_vector_type(8))) _Float16 f16x8;
typedef __attribute__((ext_vector_type(4))) float f32x4;

// ---------------------------------------------------------------- ELL build
__global__ void k_fill(const int* __restrict__ src, const int* __restrict__ dst,
                       int* __restrict__ cursor, int* __restrict__ ell, int E) {
    int e = blockIdx.x * 256 + threadIdx.x;
    if (e < E) {
        int d = dst[e];
        int slot = atomicAdd(&cursor[d], 1);
        if (slot < MAXD) ell[d * MAXD + slot] = src[e];
    }
}

__global__ void k_dinv(const int* __restrict__ cursor, float* __restrict__ dinv) {
    int i = blockIdx.x * 256 + threadIdx.x;
    dinv[i] = rsqrtf((float)(min(cursor[i], MAXD) + 1));
}

// ---------------------------------------------------------------- weight prep
// WT[n][k] = (f16)W[k][n] (MFMA B-operand needs k contiguous at fixed n).
__global__ void k_wprep(const float* __restrict__ W1, const float* __restrict__ W2,
                        const float* __restrict__ Wq, const float* __restrict__ Wk,
                        f16* __restrict__ wt) {
    const float* Ws[4] = {W1, W2, Wq, Wk};
    int k = blockIdx.x, wsel = blockIdx.y, n = threadIdx.x;
    float v = Ws[wsel][k * HD + n];              // coalesced read along n
    wt[(size_t)wsel * HD * HD + n * HD + k] = (f16)v;
}

// ---------------------------------------------------------------- MFMA GEMM
// [M,128]@[128,128] fp16 out. 64-row blocks, 4 waves, wave = 16 rows x 128
// cols = 32 mfma_f32_16x16x32_f16. Fragment math HW-verified (r6/r7):
// A/B lane l -> row/col l&15, k=(l>>4)*8+j; C/D col=l&15, row=(l>>4)*4+reg.
// SCALE: multiply output row r by dinv[r] (GCN dinv folded pre-aggregation).
// DO NOT fuse the edge-gather into this kernel (r8 lesson: gather needs
// one-wave-per-node TLP; fused = 77us vs split ~25us).
template<int AF32, int SCALE>
__global__ __launch_bounds__(256) void k_mgemm(
    const void* __restrict__ Ain, const f16* __restrict__ WT,
    const float* __restrict__ dinv, f16* __restrict__ out)
{
    __shared__ f16 Al[64][136];
    __shared__ f16 Wl[128][136];
    int t = threadIdx.x;
    int row0 = blockIdx.x * 64;
    int w = t >> 6, lane = t & 63, lr = lane & 15, lu = lane >> 4;

    if (AF32) {   // stage + cast fp32 A
        const float4* A32 = (const float4*)((const float*)Ain + (size_t)row0 * HD);
#pragma unroll
        for (int i = 0; i < 8; ++i) {
            int idx = t + 256 * i;        // 2048 = 64 rows x 32 chunks of 4 floats
            int r = idx >> 5, c4 = idx & 31;
            float4 v = A32[idx];
            f16x4 h = {(f16)v.x, (f16)v.y, (f16)v.z, (f16)v.w};
            *(f16x4*)&Al[r][c4 * 4] = h;
        }
    } else {      // stage fp16 A
        const float4* A16 = (const float4*)((const f16*)Ain + (size_t)row0 * HD);
#pragma unroll
        for (int i = 0; i < 4; ++i) {
            int idx = t + 256 * i;        // 1024 = 64 rows x 16 chunks of 8 f16
            *(float4*)&Al[idx >> 4][(idx & 15) * 8] = A16[idx];
        }
    }
    const float4* W4 = (const float4*)WT;
#pragma unroll
    for (int i = 0; i < 8; ++i) {
        int idx = t + 256 * i;            // 2048 = 128 n-rows x 16 chunks
        *(float4*)&Wl[idx >> 4][(idx & 15) * 8] = W4[idx];
    }
    __syncthreads();

    f16x8 aq[4];
#pragma unroll
    for (int ks = 0; ks < 4; ++ks)
        aq[ks] = *(const f16x8*)&Al[w * 16 + lr][ks * 32 + lu * 8];

    f32x4 acc[8];
#pragma unroll
    for (int ni = 0; ni < 8; ++ni) {
        f32x4 c = {0.f, 0.f, 0.f, 0.f};
#pragma unroll
        for (int ks = 0; ks < 4; ++ks) {
            f16x8 b = *(const f16x8*)&Wl[ni * 16 + lr][ks * 32 + lu * 8];
            c = __builtin_amdgcn_mfma_f32_16x16x32_f16(aq[ks], b, c, 0, 0, 0);
        }
        acc[ni] = c;
    }

    float dr[4] = {1.f, 1.f, 1.f, 1.f};
    if (SCALE) {
#pragma unroll
        for (int j = 0; j < 4; ++j)
            dr[j] = dinv[row0 + w * 16 + lu * 4 + j];
    }
    // epilogue: restage fp16 result in Al (dead) for coalesced float4 stores
    __syncthreads();
#pragma unroll
    for (int ni = 0; ni < 8; ++ni)
#pragma unroll
        for (int j = 0; j < 4; ++j)
            Al[w * 16 + lu * 4 + j][ni * 16 + lr] = (f16)(acc[ni][j] * dr[j]);
    __syncthreads();
    float4* O4 = (float4*)(out + (size_t)row0 * HD);
#pragma unroll
    for (int i = 0; i < 4; ++i) {
        int idx = t + 256 * i;
        O4[idx] = *(float4*)&Al[idx >> 4][(idx & 15) * 8];
    }
}

// Fused q/k projection: stage A once, two K-loops with Wl reload (r8's
// dual-GEMM restage pattern — the safe part of convB). q gets (acc+bq)*1/sqrt(H)
// folded so attn skips the score scaling; k gets (acc+bk).
__global__ __launch_bounds__(256) void k_mgemm_qk(
    const f16* __restrict__ Ain,
    const f16* __restrict__ WqT, const float* __restrict__ bq,
    const f16* __restrict__ WkT, const float* __restrict__ bk,
    f16* __restrict__ qout, f16* __restrict__ kout)
{
    __shared__ f16 Al[64][136];
    __shared__ f16 Wl[128][136];
    int t = threadIdx.x;
    int row0 = blockIdx.x * 64;
    int w = t >> 6, lane = t & 63, lr = lane & 15, lu = lane >> 4;

    const float4* A16 = (const float4*)(Ain + (size_t)row0 * HD);
#pragma unroll
    for (int i = 0; i < 4; ++i) {
        int idx = t + 256 * i;
        *(float4*)&Al[idx >> 4][(idx & 15) * 8] = A16[idx];
    }
    const float4* Wq4 = (const float4*)WqT;
#pragma unroll
    for (int i = 0; i < 8; ++i) {
        int idx = t + 256 * i;
        *(float4*)&Wl[idx >> 4][(idx & 15) * 8] = Wq4[idx];
    }
    __syncthreads();

    f16x8 aq[4];
#pragma unroll
    for (int ks = 0; ks < 4; ++ks)
        aq[ks] = *(const f16x8*)&Al[w * 16 + lr][ks * 32 + lu * 8];

    f32x4 acc[8];
#pragma unroll
    for (int ni = 0; ni < 8; ++ni) {
        f32x4 c = {0.f, 0.f, 0.f, 0.f};
#pragma unroll
        for (int ks = 0; ks < 4; ++ks) {
            f16x8 b = *(const f16x8*)&Wl[ni * 16 + lr][ks * 32 + lu * 8];
            c = __builtin_amdgcn_mfma_f32_16x16x32_f16(aq[ks], b, c, 0, 0, 0);
        }
        acc[ni] = c;
    }
    __syncthreads();                      // all reads of Al(aq) + Wl(q) done
    const float4* Wk4 = (const float4*)WkT;
#pragma unroll
    for (int i = 0; i < 8; ++i) {         // reload Wl with Wk
        int idx = t + 256 * i;
        *(float4*)&Wl[idx >> 4][(idx & 15) * 8] = Wk4[idx];
    }
#pragma unroll
    for (int ni = 0; ni < 8; ++ni)        // restage q result into Al
#pragma unroll
        for (int j = 0; j < 4; ++j)
            Al[w * 16 + lu * 4 + j][ni * 16 + lr] =
                (f16)((acc[ni][j] + bq[ni * 16 + lr]) * RSQRT_H);
    __syncthreads();                      // Al(q) + Wl(k) visible
    {
        float4* O4 = (float4*)(qout + (size_t)row0 * HD);
#pragma unroll
        for (int i = 0; i < 4; ++i) {
            int idx = t + 256 * i;
            O4[idx] = *(float4*)&Al[idx >> 4][(idx & 15) * 8];
        }
    }
#pragma unroll
    for (int ni = 0; ni < 8; ++ni) {
        f32x4 c = {0.f, 0.f, 0.f, 0.f};
#pragma unroll
        for (int ks = 0; ks < 4; ++ks) {
            f16x8 b = *(const f16x8*)&Wl[ni * 16 + lr][ks * 32 + lu * 8];
            c = __builtin_amdgcn_mfma_f32_16x16x32_f16(aq[ks], b, c, 0, 0, 0);
        }
        acc[ni] = c;
    }
    __syncthreads();                      // q-stores done reading Al
#pragma unroll
    for (int ni = 0; ni < 8; ++ni)
#pragma unroll
        for (int j = 0; j < 4; ++j)
            Al[w * 16 + lu * 4 + j][ni * 16 + lr] =
                (f16)(acc[ni][j] + bk[ni * 16 + lr]);
    __syncthreads();
    {
        float4* O4 = (float4*)(kout + (size_t)row0 * HD);
#pragma unroll
        for (int i = 0; i < 4; ++i) {
            int idx = t + 256 * i;
            O4[idx] = *(float4*)&Al[idx >> 4][(idx & 15) * 8];
        }
    }
}

// ---------------------------------------------------------------- aggregation
// one 64-lane wave per node; rows pre-scaled by dinv_s in the GEMM epilogue,
// so the inner loop is pure gather+add: int4 edge-index load, 4 half2 loads.
// h_i = relu(dinv_i * (sum_{s in N(i) u {i}} ts_s) + b).
__global__ __launch_bounds__(256) void k_agg(
    const __half* __restrict__ tmat, const int* __restrict__ cursor,
    const float* __restrict__ dinv, const int* __restrict__ ell,
    const float* __restrict__ bias, __half* __restrict__ hout)
{
    int t = threadIdx.x;
    int i = blockIdx.x * 4 + (t >> 6);   // node
    int lane = t & 63;                   // feature pair index
    int cnt = min(cursor[i], MAXD);
    float di = dinv[i];
    float2 sv = __half22float2(((const __half2*)(tmat + (size_t)i * HD))[lane]);
    float a0 = sv.x, a1 = sv.y;          // self (already dinv_i-scaled)
    const int* row = ell + (size_t)i * MAXD;
    int e = 0;
    for (; e + 4 <= cnt; e += 4) {       // 4 edges per iter, one int4 index load
        int4 s = *(const int4*)&row[e];
        float2 v0 = __half22float2(((const __half2*)(tmat + (size_t)s.x * HD))[lane]);
        float2 v1 = __half22float2(((const __half2*)(tmat + (size_t)s.y * HD))[lane]);
        float2 v2 = __half22float2(((const __half2*)(tmat + (size_t)s.z * HD))[lane]);
        float2 v3 = __half22float2(((const __half2*)(tmat + (size_t)s.w * HD))[lane]);
        a0 += v0.x + v1.x + v2.x + v3.x;
        a1 += v0.y + v1.y + v2.y + v3.y;
    }
    for (; e < cnt; ++e) {
        int s0 = row[e];
        float2 v0 = __half22float2(((const __half2*)(tmat + (size_t)s0 * HD))[lane]);
        a0 += v0.x;
        a1 += v0.y;
    }
    __half2 o;
    o.x = __float2half(fmaxf(di * a0 + bias[lane * 2], 0.f));
    o.y = __float2half(fmaxf(di * a1 + bias[lane * 2 + 1], 0.f));
    ((__half2*)(hout + (size_t)i * HD))[lane] = o;
}

// ---------------------------------------------------------------- attention
// MFMA QK^T, double-buffered K. XCD-aware decode: bid = qt*64 + g, so the 8
// q-tile blocks of one graph land on the SAME XCD (bid%8 == g%8) and share
// the 128KB K-tile in that XCD's L2 instead of re-fetching it 8x.
// q is pre-scaled by 1/sqrt(H) at projection time.
__global__ __launch_bounds__(256, 2) void k_attn(
    const __half* __restrict__ qh,  // [N][128] fp16, pre-scaled by 1/sqrt(H)
    const __half* __restrict__ kh,  // [N][128] fp16
    float* __restrict__ wpart)      // [64*8][512]
{
    __shared__ f16 Kl[2][64][136];
    __shared__ float wlp[4][512];
    int t = threadIdx.x;
    int g = blockIdx.x & 63;
    int qt = blockIdx.x >> 6;
    int w = t >> 6, lane = t & 63;
    int lr = lane & 15, lu = lane >> 4;
    int qrow0 = g * NPG + qt * 64;

    f16x8 aq[4];
    {
        const f16* qp = (const f16*)qh + (size_t)(qrow0 + w * 16 + lr) * HD + lu * 8;
#pragma unroll
        for (int ks = 0; ks < 4; ++ks)
            aq[ks] = *(const f16x8*)(qp + ks * 32);
    }
    // stage tile 0 into buffer 0
    {
        const float4* ks4 = (const float4*)(kh + (size_t)(g * NPG) * HD);
#pragma unroll
        for (int i = 0; i < 4; ++i) {
            int idx = t + 256 * i;
            *(float4*)&Kl[0][idx >> 4][(idx & 15) * 8] = ks4[idx];
        }
    }

    f32x4 p[8][4];       // [mt][ni], statically indexed
#pragma unroll
    for (int mt = 0; mt < 8; ++mt) {
        __syncthreads();                 // buf[mt&1] ready; prev compute done
        if (mt < 7) {
            const float4* ks4 = (const float4*)(kh + (size_t)(g * NPG + (mt + 1) * 64) * HD);
#pragma unroll
            for (int i = 0; i < 4; ++i) {
                int idx = t + 256 * i;
                *(float4*)&Kl[(mt + 1) & 1][idx >> 4][(idx & 15) * 8] = ks4[idx];
            }
        }
#pragma unroll
        for (int ni = 0; ni < 4; ++ni) {
            f32x4 acc = {0.f, 0.f, 0.f, 0.f};
#pragma unroll
            for (int ks = 0; ks < 4; ++ks) {
                f16x8 b = *(const f16x8*)&Kl[mt & 1][ni * 16 + lr][ks * 32 + lu * 8];
                acc = __builtin_amdgcn_mfma_f32_16x16x32_f16(aq[ks], b, acc, 0, 0, 0);
            }
            p[mt][ni] = acc;
        }
    }

    // row max per reg j (row = 16w + 4*lu + j)
    float mrow[4], linv[4];
#pragma unroll
    for (int j = 0; j < 4; ++j) {
        float m = p[0][0][j];
#pragma unroll
        for (int mt = 0; mt < 8; ++mt)
#pragma unroll
            for (int ni = 0; ni < 4; ++ni) m = fmaxf(m, p[mt][ni][j]);
        m = fmaxf(m, __shfl_xor(m, 1));
        m = fmaxf(m, __shfl_xor(m, 2));
        m = fmaxf(m, __shfl_xor(m, 4));
        m = fmaxf(m, __shfl_xor(m, 8));
        mrow[j] = m;
    }
#pragma unroll
    for (int mt = 0; mt < 8; ++mt)
#pragma unroll
        for (int ni = 0; ni < 4; ++ni)
#pragma unroll
            for (int j = 0; j < 4; ++j)
                p[mt][ni][j] = __expf(p[mt][ni][j] - mrow[j]);
#pragma unroll
    for (int j = 0; j < 4; ++j) {
        float l = 0.f;
#pragma unroll
        for (int mt = 0; mt < 8; ++mt)
#pragma unroll
            for (int ni = 0; ni < 4; ++ni) l += p[mt][ni][j];
        l += __shfl_xor(l, 1);
        l += __shfl_xor(l, 2);
        l += __shfl_xor(l, 4);
        l += __shfl_xor(l, 8);
        linv[j] = 1.f / l;
    }
    // column sums of normalized attention -> per-wave slice (no atomics)
#pragma unroll
    for (int mt = 0; mt < 8; ++mt)
#pragma unroll
        for (int ni = 0; ni < 4; ++ni) {
            float pc = p[mt][ni][0] * linv[0] + p[mt][ni][1] * linv[1]
                     + p[mt][ni][2] * linv[2] + p[mt][ni][3] * linv[3];
            pc += __shfl_xor(pc, 16);
            pc += __shfl_xor(pc, 32);
            if (lu == 0) wlp[w][mt * 64 + ni * 16 + lr] = pc;
        }
    __syncthreads();
    float* wp = wpart + ((size_t)(g * 8 + qt)) * NPG;
    wp[t] = (wlp[0][t] + wlp[1][t] + wlp[2][t] + wlp[3][t]) * (1.f / NPG);
    wp[t + 256] = (wlp[0][t + 256] + wlp[1][t + 256] + wlp[2][t + 256]
                 + wlp[3][t + 256]) * (1.f / NPG);
}

// ---------------------------------------------------------------- pool + head
// One block per graph: w = sum of qt slices; u = sum_m w[m] h[m]; then MLP.
__global__ __launch_bounds__(256) void k_poolhead(
    const float* __restrict__ wpart, const __half* __restrict__ h,
    const float* __restrict__ Wv, const float* __restrict__ bv,
    const float* __restrict__ Wh1, const float* __restrict__ bh1,
    const float* __restrict__ Wh2, const float* __restrict__ bh2,
    float* __restrict__ out)
{
    __shared__ float wloc[512];
    __shared__ float upar[2][128];
    __shared__ float ul[128];
    __shared__ float pl[128];
    __shared__ float r1l[64];
    int g = blockIdx.x, t = threadIdx.x;
    {
        float w0 = 0.f, w1 = 0.f;
#pragma unroll
        for (int qt = 0; qt < 8; ++qt) {
            const float* wp = wpart + ((size_t)(g * 8 + qt)) * NPG;
            w0 += wp[t]; w1 += wp[t + 256];
        }
        wloc[t] = w0; wloc[t + 256] = w1;
    }
    __syncthreads();
    int col = t & 127, half = t >> 7;
    const __half* hg = h + ((size_t)g * NPG + half * 256) * HD;
    float u = 0.f;
#pragma unroll 4
    for (int m = 0; m < 256; ++m)
        u += wloc[half * 256 + m] * __half2float(hg[(size_t)m * HD + col]);
    upar[half][col] = u;
    __syncthreads();
    if (t < 128) ul[t] = upar[0][t] + upar[1][t];
    __syncthreads();
    if (t < 128) {
        float pv = bv[t];
        for (int d = 0; d < HD; ++d) pv += ul[d] * Wv[d * HD + t];
        pl[t] = pv;
    }
    __syncthreads();
    if (t < 64) {
        float r1 = bh1[t];
        for (int d = 0; d < HD; ++d) r1 += pl[d] * Wh1[d * 64 + t];
        r1l[t] = fmaxf(r1, 0.f);
    }
    __syncthreads();
    if (t == 0) {
        float o = bh2[0];
        for (int j = 0; j < 64; ++j) o += r1l[j] * Wh2[j];
        out[g] = o;
    }
}

// ---------------------------------------------------------------- launch
extern "C" void kernel_launch(void* const* d_in, const int* in_sizes, int n_in,
                              void* d_out, int out_size, void* d_ws, size_t ws_size,
                              hipStream_t stream) {
    const float* x   = (const float*)d_in[0];
    const int* edge  = (const int*)d_in[1];
    // d_in[2] = batch (unused: batch = arange // 512 exactly)
    const float* W1  = (const float*)d_in[3];
    const float* b1  = (const float*)d_in[4];
    const float* W2  = (const float*)d_in[5];
    const float* b2  = (const float*)d_in[6];
    const float* Wq  = (const float*)d_in[7];
    const float* bq  = (const float*)d_in[8];
    const float* Wk  = (const float*)d_in[9];
    const float* bk  = (const float*)d_in[10];
    const float* Wv  = (const float*)d_in[11];
    const float* bv  = (const float*)d_in[12];
    const float* Wh1 = (const float*)d_in[13];
    const float* bh1 = (const float*)d_in[14];
    const float* Wh2 = (const float*)d_in[15];
    const float* bh2 = (const float*)d_in[16];
    float* out = (float*)d_out;

    int E = in_sizes[1] / 2;
    const int* src = edge;
    const int* dst = edge + E;

    // workspace layout (~51 MB):
    //  region1 [16MB]: tmat fp16 (conv) -> qh fp16 | kh fp16
    //  region2 [16MB]: hbuf fp16 (first 8MB)
    //  region3 [16MB]: ell int[N][64] (8MB)
    //  wpart | cursor | wtb | dinv
    f16* tmat = (f16*)d_ws;                          // [N][128] fp16
    f16* qh   = tmat;                                // overlays tmat after aggs
    f16* kh   = qh + (size_t)NN * HD;                // second 8MB of region1
    __half* hbuf = (__half*)(kh + (size_t)NN * HD);  // region2 (8MB used)
    int* ell = (int*)((f16*)hbuf + 2 * (size_t)NN * HD);  // region3
    float* wpart = (float*)(ell + (size_t)NN * MAXD);     // [64*8][512]
    int* cursor = (int*)(wpart + GG * 8 * NPG);      // [N]
    f16* wtb    = (f16*)(cursor + NN);               // [4][128][128] fp16
    float* dinv = (float*)(wtb + 4 * HD * HD);       // [N]
    f16* W1T = wtb, *W2T = wtb + HD * HD, *WqT = wtb + 2 * HD * HD,
       * WkT = wtb + 3 * HD * HD;

    int eb = (E + 255) / 256;

    // graph structure + weight prep
    hipMemsetAsync(cursor, 0, NN * sizeof(int), stream);
    k_fill<<<eb, 256, 0, stream>>>(src, dst, cursor, ell, E);
    k_dinv<<<NN / 256, 256, 0, stream>>>(cursor, dinv);
    k_wprep<<<dim3(HD, 4), HD, 0, stream>>>(W1, W2, Wq, Wk, wtb);

    // conv1: tmat = (x @ W1) * dinv_row
    k_mgemm<1, 1><<<NN / 64, 256, 0, stream>>>(x, W1T, dinv, tmat);
    k_agg<<<NN / 4, 256, 0, stream>>>((const __half*)tmat, cursor, dinv, ell, b1, hbuf);
    // conv2: tmat = (h1 @ W2) * dinv_row
    k_mgemm<0, 1><<<NN / 64, 256, 0, stream>>>(hbuf, W2T, dinv, tmat);
    k_agg<<<NN / 4, 256, 0, stream>>>((const __half*)tmat, cursor, dinv, ell, b2, hbuf);
    // q (pre-scaled by 1/sqrt(H)) + k in one kernel
    k_mgemm_qk<<<NN / 64, 256, 0, stream>>>((const f16*)hbuf, WqT, bq, WkT, bk, qh, kh);
    // attention column weights via MFMA (XCD-swizzled, double-buffered K)
    k_attn<<<GG * 8, 256, 0, stream>>>((const __half*)qh, (const __half*)kh, wpart);
    // pool + MLP head, one block per graph
    k_poolhead<<<GG, 256, 0, stream>>>(wpart, hbuf, Wv, bv, Wh1, bh1, Wh2, bh2, out);
}